// Round 22
// baseline (97.834 us; speedup 1.0000x reference)
//
#include <hip/hip_runtime.h>

#define NSTEPS 80
#define BATCH  65536
#define NIN    20
#define NHID   10
#define NOUT   2
#define NH2    5      // hidden neurons per lane (NHID/2)
#define NW     12     // floats loaded per lane per step (3 x float4 window)

typedef float v2f __attribute__((ext_vector_type(2)));

// Non-temporal 8B store — outputs are write-once; keep them out of L2.
__device__ __forceinline__ void st_nt2(float* p, float2 v) {
  union { float2 f; double d; } u; u.f = v;
  __builtin_nontemporal_store(u.d, reinterpret_cast<double*>(p));
}

// Windowed x load: lane h of a pair loads 12 of the row's 20 floats.
//   h=0: k0..11 (row+0), h=1: k8..19 (row+32B). 3 float4 each.
__device__ __forceinline__ void load_x12(float* __restrict__ W,
                                         const float* __restrict__ row, int h) {
  const float* src = row + h * 8;
#pragma unroll
  for (int c = 0; c < 3; ++c) {
    const float4 v = *reinterpret_cast<const float4*>(src + 4 * c);
    W[4 * c + 0] = v.x; W[4 * c + 1] = v.y; W[4 * c + 2] = v.z; W[4 * c + 3] = v.w;
  }
}

// Reassemble the full 20-float row from own window + partner's window.
// 12 shfl_xor(.,1) move bits; h-selects pick source. Bits MOVED, never
// recomputed -> bit-identical numerics.
__device__ __forceinline__ void gather_x20(float (&xb)[NIN],
                                           const float (&W)[NW], int h) {
  float R[NW];
#pragma unroll
  for (int j = 0; j < NW; ++j) R[j] = __shfl_xor(W[j], 1);
#pragma unroll
  for (int k = 0; k < 8; ++k)  xb[k]      = h ? R[k]     : W[k];      // k0..7
#pragma unroll
  for (int k = 0; k < 4; ++k)  xb[8 + k]  = h ? W[k]     : W[8 + k];  // k8..11
#pragma unroll
  for (int k = 0; k < 4; ++k)  xb[12 + k] = h ? W[4 + k] : R[4 + k];  // k12..15
#pragma unroll
  for (int k = 0; k < 4; ++k)  xb[16 + k] = h ? W[8 + k] : R[8 + k];  // k16..19
}

// One SNN timestep, 2 lanes per batch element (split by hidden neuron).
// VERIFIED NUMERICS (R15) bit-exact: each neuron's chain sequential
// ascending-k (own accumulator lane of v_pk_fma_f32 = separately-rounded
// IEEE FMA), bias after, fmaf(0.5,mem,cur)-reset, spike mem >= 1.0f
// (np.heaviside(x,1) fires at exactly-zero argument).
__device__ __forceinline__ void snn_step2(
    const float (&xb)[NIN], int h,
    const v2f (&w1p)[2][NIN], const float (&w1s)[NIN], const float (&bb1)[NH2],
    const v2f (&w2p)[NHID], const float (&bb2)[NOUT],
    float (&mem1)[NH2], float (&mem2)[NOUT],
    float2& spk_out, float2& mem_out)
{
  v2f a01; a01.x = 0.0f; a01.y = 0.0f;
  v2f a23; a23.x = 0.0f; a23.y = 0.0f;
  float a4 = 0.0f;
#pragma unroll
  for (int k = 0; k < NIN; ++k) {
    v2f xk; xk.x = xb[k]; xk.y = xb[k];
    a01 = __builtin_elementwise_fma(xk, w1p[0][k], a01);
    a23 = __builtin_elementwise_fma(xk, w1p[1][k], a23);
    a4  = fmaf(xb[k], w1s[k], a4);
  }
  const float accs[NH2] = {a01.x, a01.y, a23.x, a23.y, a4};
  float a[NH2];
#pragma unroll
  for (int jj = 0; jj < NH2; ++jj) {
    const float cur = accs[jj] + bb1[jj];
    const float reset = (mem1[jj] >= 1.0f) ? 1.0f : 0.0f;
    const float m = fmaf(0.5f, mem1[jj], cur) - reset;
    mem1[jj] = m;
    a[jj] = (m >= 1.0f) ? 1.0f : 0.0f;
  }
  float o5[NH2];
#pragma unroll
  for (int jj = 0; jj < NH2; ++jj) o5[jj] = __shfl_xor(a[jj], 1);
  float s[NHID];
#pragma unroll
  for (int j = 0; j < NH2; ++j)  s[j]       = h ? o5[j] : a[j];
#pragma unroll
  for (int j = 0; j < NH2; ++j)  s[NH2 + j] = h ? a[j]  : o5[j];
  v2f c2; c2.x = 0.0f; c2.y = 0.0f;
#pragma unroll
  for (int j = 0; j < NHID; ++j) {
    v2f sj; sj.x = s[j]; sj.y = s[j];
    c2 = __builtin_elementwise_fma(sj, w2p[j], c2);
  }
#pragma unroll
  for (int o = 0; o < NOUT; ++o) {
    const float cur = ((o == 0) ? c2.x : c2.y) + bb2[o];
    const float reset = (mem2[o] >= 1.0f) ? 1.0f : 0.0f;
    mem2[o] = fmaf(0.5f, mem2[o], cur) - reset;
  }
  spk_out = make_float2((mem2[0] >= 1.0f) ? 1.0f : 0.0f,
                        (mem2[1] >= 1.0f) ? 1.0f : 0.0f);
  mem_out = make_float2(mem2[0], mem2[1]);
}

// 2 threads/elem = 2 waves/SIMD; windowed loads; prefetch distance 3
// (4 rotating windows) to deepen the HBM read queue across the scattered
// store bursts. ~200 VGPR at launch_bounds(256,2).
__global__ __launch_bounds__(256, 2)
void snn_forward2(const float* __restrict__ x,
                  const float* __restrict__ W1, const float* __restrict__ B1,
                  const float* __restrict__ W2, const float* __restrict__ B2,
                  float* __restrict__ out)
{
  const int i = blockIdx.x * blockDim.x + threadIdx.x;   // 0..2*BATCH-1
  const int b = i >> 1;
  const int h = i & 1;
  const int j0 = NH2 * h;

  v2f w1p[2][NIN];
  float w1s[NIN];
#pragma unroll
  for (int p = 0; p < 2; ++p)
#pragma unroll
    for (int k = 0; k < NIN; ++k) {
      v2f t; t.x = W1[(j0 + 2 * p) * NIN + k]; t.y = W1[(j0 + 2 * p + 1) * NIN + k];
      w1p[p][k] = t;
    }
#pragma unroll
  for (int k = 0; k < NIN; ++k) w1s[k] = W1[(j0 + 4) * NIN + k];
  float bb1[NH2];
#pragma unroll
  for (int jj = 0; jj < NH2; ++jj) bb1[jj] = B1[j0 + jj];
  v2f w2p[NHID];
#pragma unroll
  for (int j = 0; j < NHID; ++j) {
    v2f t; t.x = W2[j]; t.y = W2[NHID + j];
    w2p[j] = t;
  }
  float bb2[NOUT] = {B2[0], B2[1]};

  float mem1[NH2];
#pragma unroll
  for (int jj = 0; jj < NH2; ++jj) mem1[jj] = 0.0f;
  float mem2[NOUT] = {0.0f, 0.0f};

  const size_t ss = (size_t)BATCH * NIN;
  const size_t os = (size_t)BATCH * NOUT;
  const float* xp = x + (size_t)b * NIN;
  float* op = out + (h ? (size_t)NSTEPS * BATCH * NOUT : 0) + (size_t)b * NOUT;

  float A[NW], Bb[NW], C[NW], D[NW];
  load_x12(A,  xp,          h);
  load_x12(Bb, xp + 1 * ss, h);
  load_x12(C,  xp + 2 * ss, h);

#define SNN_STEP_EMIT(BUF)                                           \
  {                                                                  \
    float xb[NIN];                                                   \
    gather_x20(xb, BUF, h);                                          \
    float2 s_, m_;                                                   \
    snn_step2(xb, h, w1p, w1s, bb1, w2p, bb2, mem1, mem2, s_, m_);   \
    st_nt2(op, h ? m_ : s_);                                         \
    op += os;                                                        \
  }

  // main loop: t = 0,4,...,72 (19 iters, steps 0..75, prefetch max 78)
  for (int t = 0; t <= 72; t += 4) {
    load_x12(D,  xp + (size_t)(t + 3) * ss, h);
    SNN_STEP_EMIT(A);
    load_x12(A,  xp + (size_t)(t + 4) * ss, h);
    SNN_STEP_EMIT(Bb);
    load_x12(Bb, xp + (size_t)(t + 5) * ss, h);
    SNN_STEP_EMIT(C);
    load_x12(C,  xp + (size_t)(t + 6) * ss, h);
    SNN_STEP_EMIT(D);
  }
  // after t=72 iter: A=76, Bb=77, C=78 loaded; steps 72..75 done
  load_x12(D, xp + (size_t)79 * ss, h);
  SNN_STEP_EMIT(A);   // t = 76
  SNN_STEP_EMIT(Bb);  // t = 77
  SNN_STEP_EMIT(C);   // t = 78
  SNN_STEP_EMIT(D);   // t = 79
#undef SNN_STEP_EMIT
}

extern "C" void kernel_launch(void* const* d_in, const int* in_sizes, int n_in,
                              void* d_out, int out_size, void* d_ws, size_t ws_size,
                              hipStream_t stream) {
  (void)in_sizes; (void)n_in; (void)d_ws; (void)ws_size; (void)out_size;
  const float* x  = (const float*)d_in[0];
  const float* W1 = (const float*)d_in[1];
  const float* B1 = (const float*)d_in[2];
  const float* W2 = (const float*)d_in[3];
  const float* B2 = (const float*)d_in[4];
  float* out = (float*)d_out;

  dim3 grid(2 * BATCH / 256), block(256);
  snn_forward2<<<grid, block, 0, stream>>>(x, W1, B1, W2, B2, out);
}

// Round 23
// 96.646 us; speedup vs baseline: 1.0123x; 1.0123x over previous
//
#include <hip/hip_runtime.h>

#define NSTEPS 80
#define BATCH  65536
#define NIN    20
#define NHID   10
#define NOUT   2
#define NH2    5      // hidden neurons per lane (NHID/2)
#define NW     12     // floats loaded per lane per step (3 x float4 window)

// Non-temporal 8B store — outputs are write-once; keep them out of L2.
__device__ __forceinline__ void st_nt2(float* p, float2 v) {
  union { float2 f; double d; } u; u.f = v;
  __builtin_nontemporal_store(u.d, reinterpret_cast<double*>(p));
}

// Windowed x load: lane h of a pair loads 12 of the row's 20 floats.
//   h=0: k0..11 (row+0), h=1: k8..19 (row+32B). 3 float4 each ->
//   6 VMEM instrs per pair per step instead of 10 (no duplicate addresses).
__device__ __forceinline__ void load_x12(float* __restrict__ W,
                                         const float* __restrict__ row, int h) {
  const float* src = row + h * 8;   // h=1 starts at k=8
#pragma unroll
  for (int c = 0; c < 3; ++c) {
    const float4 v = *reinterpret_cast<const float4*>(src + 4 * c);
    W[4 * c + 0] = v.x; W[4 * c + 1] = v.y; W[4 * c + 2] = v.z; W[4 * c + 3] = v.w;
  }
}

// Reassemble the full 20-float row from own window + partner's window.
// 12 shfl_xor(.,1) (DPP pair swap) move bits; h-selects pick source.
// Values are MOVED, never recomputed -> bit-identical to verified numerics.
__device__ __forceinline__ void gather_x20(float (&xb)[NIN],
                                           const float (&W)[NW], int h) {
  float R[NW];
#pragma unroll
  for (int j = 0; j < NW; ++j) R[j] = __shfl_xor(W[j], 1);
#pragma unroll
  for (int k = 0; k < 8; ++k)  xb[k]      = h ? R[k]     : W[k];      // k0..7
#pragma unroll
  for (int k = 0; k < 4; ++k)  xb[8 + k]  = h ? W[k]     : W[8 + k];  // k8..11
#pragma unroll
  for (int k = 0; k < 4; ++k)  xb[12 + k] = h ? W[4 + k] : R[4 + k];  // k12..15
#pragma unroll
  for (int k = 0; k < 4; ++k)  xb[16 + k] = h ? W[8 + k] : R[8 + k];  // k16..19
}

// One SNN timestep, 2 lanes per batch element (split by hidden neuron).
// VERIFIED NUMERICS (R15) preserved bit-exactly: zero-init ascending-k
// fused-FMA chains, bias after, fmaf(0.5,mem,cur)-reset, spike mem>=1.0f
// (np.heaviside(x,1) fires at exactly-zero argument).
__device__ __forceinline__ void snn_step2(
    const float (&xb)[NIN], int h,
    const float (&w1)[NH2][NIN], const float (&bb1)[NH2],
    const float (&w2)[NOUT][NHID], const float (&bb2)[NOUT],
    float (&mem1)[NH2], float (&mem2)[NOUT],
    float2& spk_out, float2& mem_out)
{
  float a[NH2];
#pragma unroll
  for (int jj = 0; jj < NH2; ++jj) {
    float acc = 0.0f;
#pragma unroll
    for (int k = 0; k < NIN; ++k) acc = fmaf(xb[k], w1[jj][k], acc);
    const float cur = acc + bb1[jj];
    const float reset = (mem1[jj] >= 1.0f) ? 1.0f : 0.0f;
    const float m = fmaf(0.5f, mem1[jj], cur) - reset;
    mem1[jj] = m;
    a[jj] = (m >= 1.0f) ? 1.0f : 0.0f;
  }
  float o5[NH2];
#pragma unroll
  for (int jj = 0; jj < NH2; ++jj) o5[jj] = __shfl_xor(a[jj], 1);
  float s[NHID];
#pragma unroll
  for (int j = 0; j < NH2; ++j)  s[j]       = h ? o5[j] : a[j];
#pragma unroll
  for (int j = 0; j < NH2; ++j)  s[NH2 + j] = h ? a[j]  : o5[j];
#pragma unroll
  for (int o = 0; o < NOUT; ++o) {
    float acc = 0.0f;
#pragma unroll
    for (int j = 0; j < NHID; ++j) acc = fmaf(s[j], w2[o][j], acc);
    const float cur = acc + bb2[o];
    const float reset = (mem2[o] >= 1.0f) ? 1.0f : 0.0f;
    mem2[o] = fmaf(0.5f, mem2[o], cur) - reset;
  }
  spk_out = make_float2((mem2[0] >= 1.0f) ? 1.0f : 0.0f,
                        (mem2[1] >= 1.0f) ? 1.0f : 0.0f);
  mem_out = make_float2(mem2[0], mem2[1]);
}

// 2 threads/elem = 2 waves/SIMD (TLP) + windowed loads (no dup VMEM).
// ~210 VGPR at launch_bounds(256,2); 3 rotating 12-float windows keep
// >=2 steps of x in flight. Empirical best of the R15-R22 sweep.
__global__ __launch_bounds__(256, 2)
void snn_forward2(const float* __restrict__ x,
                  const float* __restrict__ W1, const float* __restrict__ B1,
                  const float* __restrict__ W2, const float* __restrict__ B2,
                  float* __restrict__ out)
{
  const int i = blockIdx.x * blockDim.x + threadIdx.x;   // 0..2*BATCH-1
  const int b = i >> 1;
  const int h = i & 1;
  const int j0 = NH2 * h;

  float w1[NH2][NIN];
#pragma unroll
  for (int jj = 0; jj < NH2; ++jj)
#pragma unroll
    for (int k = 0; k < NIN; k += 4) {
      const float4 v = *reinterpret_cast<const float4*>(W1 + (j0 + jj) * NIN + k);
      w1[jj][k] = v.x; w1[jj][k + 1] = v.y; w1[jj][k + 2] = v.z; w1[jj][k + 3] = v.w;
    }
  float bb1[NH2];
#pragma unroll
  for (int jj = 0; jj < NH2; ++jj) bb1[jj] = B1[j0 + jj];
  float w2[NOUT][NHID];
#pragma unroll
  for (int o = 0; o < NOUT; ++o)
#pragma unroll
    for (int j = 0; j < NHID; ++j) w2[o][j] = W2[o * NHID + j];
  float bb2[NOUT];
#pragma unroll
  for (int o = 0; o < NOUT; ++o) bb2[o] = B2[o];

  float mem1[NH2];
#pragma unroll
  for (int jj = 0; jj < NH2; ++jj) mem1[jj] = 0.0f;
  float mem2[NOUT] = {0.0f, 0.0f};

  const size_t ss = (size_t)BATCH * NIN;
  const size_t os = (size_t)BATCH * NOUT;
  const float* xp = x + (size_t)b * NIN;
  float* op = out + (h ? (size_t)NSTEPS * BATCH * NOUT : 0) + (size_t)b * NOUT;

  float A[NW], Bb[NW], C[NW];
  load_x12(A,  xp,      h);
  load_x12(Bb, xp + ss, h);

#define SNN_STEP_EMIT(BUF)                                           \
  {                                                                  \
    float xb[NIN];                                                   \
    gather_x20(xb, BUF, h);                                          \
    float2 s_, m_;                                                   \
    snn_step2(xb, h, w1, bb1, w2, bb2, mem1, mem2, s_, m_);          \
    st_nt2(op, h ? m_ : s_);                                         \
    op += os;                                                        \
  }

  // 26 iters cover t=0..77 (prefetch indices <= 79: no guards needed)
  for (int t = 0; t < 78; t += 3) {
    load_x12(C,  xp + (size_t)(t + 2) * ss, h);
    SNN_STEP_EMIT(A);
    load_x12(A,  xp + (size_t)(t + 3) * ss, h);
    SNN_STEP_EMIT(Bb);
    load_x12(Bb, xp + (size_t)(t + 4) * ss, h);
    SNN_STEP_EMIT(C);
  }
  SNN_STEP_EMIT(A);   // t = 78
  SNN_STEP_EMIT(Bb);  // t = 79
#undef SNN_STEP_EMIT
}

extern "C" void kernel_launch(void* const* d_in, const int* in_sizes, int n_in,
                              void* d_out, int out_size, void* d_ws, size_t ws_size,
                              hipStream_t stream) {
  (void)in_sizes; (void)n_in; (void)d_ws; (void)ws_size; (void)out_size;
  const float* x  = (const float*)d_in[0];
  const float* W1 = (const float*)d_in[1];
  const float* B1 = (const float*)d_in[2];
  const float* W2 = (const float*)d_in[3];
  const float* B2 = (const float*)d_in[4];
  float* out = (float*)d_out;

  dim3 grid(2 * BATCH / 256), block(256);
  snn_forward2<<<grid, block, 0, stream>>>(x, W1, B1, W2, B2, out);
}